// Round 1
// baseline (2962.022 us; speedup 1.0000x reference)
//
#include <hip/hip_runtime.h>
#include <hip/hip_bf16.h>
#include <stdint.h>

// ---------------- level metadata (from torch-ngp GridEncoder __init__) -------
// l=0..2 dense (res+1 = 17/33/65), l>=3 hashed, hsize = 2^19
__device__ const int d_level_off[16] = {
    0, 4920, 40864, 315496, 839784, 1364072, 1888360, 2412648,
    2936936, 3461224, 3985512, 4509800, 5034088, 5558376, 6082664, 6606952
};

// ---------------- grid encode + affordance embedding -------------------------
// one thread per (point, level); writes comb[n, l*8 .. l*8+7]
__global__ __launch_bounds__(256) void grid_encode_kernel(
    const float* __restrict__ x, const float* __restrict__ aff,
    const float* __restrict__ table, const float* __restrict__ Wa,
    const float* __restrict__ ba, float* __restrict__ comb, int npts)
{
    int t = blockIdx.x * 256 + threadIdx.x;
    int n = t >> 4;
    if (n >= npts) return;
    int l = t & 15;

    float scale = (float)((16 << l) - 1);
    float fr[3];
    uint32_t cc[3];
    #pragma unroll
    for (int d = 0; d < 3; ++d) {
        float b   = (x[n * 3 + d] + 10.0f) / 20.0f;   // [-10,10] -> [0,1]
        float x01 = (b + 1.0f) * 0.5f;                // -> [0.5,1]
        float pos = x01 * scale + 0.5f;
        float pg  = floorf(pos);
        fr[d] = pos - pg;
        cc[d] = (uint32_t)(int)pg;
    }

    const bool dense = (l < 3);
    const uint32_t s1 = (uint32_t)(16 << l) + 1u;
    const uint32_t s2 = s1 * s1;
    const int off = d_level_off[l];

    float fa[8] = {0.f, 0.f, 0.f, 0.f, 0.f, 0.f, 0.f, 0.f};
    #pragma unroll
    for (int c = 0; c < 8; ++c) {
        uint32_t cx = cc[0] + (uint32_t)(c & 1);
        uint32_t cy = cc[1] + (uint32_t)((c >> 1) & 1);
        uint32_t cz = cc[2] + (uint32_t)((c >> 2) & 1);
        float w = ((c & 1) ? fr[0] : 1.0f - fr[0])
                * ((c & 2) ? fr[1] : 1.0f - fr[1])
                * ((c & 4) ? fr[2] : 1.0f - fr[2]);
        uint32_t idx;
        if (dense) idx = cx + cy * s1 + cz * s2;
        else       idx = (cx ^ (cy * 2654435761u) ^ (cz * 805459861u)) & 0x7FFFFu;
        const float4* p = (const float4*)(table + (size_t)(idx + (uint32_t)off) * 8u);
        float4 t0 = p[0];
        float4 t1 = p[1];
        fa[0] = fmaf(w, t0.x, fa[0]);
        fa[1] = fmaf(w, t0.y, fa[1]);
        fa[2] = fmaf(w, t0.z, fa[2]);
        fa[3] = fmaf(w, t0.w, fa[3]);
        fa[4] = fmaf(w, t1.x, fa[4]);
        fa[5] = fmaf(w, t1.y, fa[5]);
        fa[6] = fmaf(w, t1.z, fa[6]);
        fa[7] = fmaf(w, t1.w, fa[7]);
    }

    float av = aff[n];
    int fb = l * 8;
    float o[8];
    #pragma unroll
    for (int j = 0; j < 8; ++j)
        o[j] = fa[j] + av * Wa[fb + j] + ba[fb + j];
    float* dst = comb + (size_t)n * 128 + fb;
    *(float4*)dst       = *(float4*)&o[0];
    *(float4*)(dst + 4) = *(float4*)&o[4];
}

// ---------------- tiny precompute GEMMs (weight folding) ---------------------
// C[j,k] = sum_i A[j*Ko+i] * B[i*No+k]   (A: [Mo,Ko] row-major, B: [Ko,No] row-major)
__global__ void small_mm(const float* __restrict__ A, const float* __restrict__ B,
                         float* __restrict__ C, int Mo, int No, int Ko)
{
    int gid = blockIdx.x * 256 + threadIdx.x;
    if (gid >= Mo * No) return;
    int j = gid / No, k = gid % No;
    float s = 0.f;
    for (int i = 0; i < Ko; ++i) s = fmaf(A[j * Ko + i], B[i * No + k], s);
    C[gid] = s;
}

// out[j] = b0[j] + sum_i A[j*Ko+i] * v[i]
__global__ void small_mv(const float* __restrict__ A, const float* __restrict__ v,
                         const float* __restrict__ b0, float* __restrict__ out,
                         int Mo, int Ko)
{
    int j = blockIdx.x * 256 + threadIdx.x;
    if (j >= Mo) return;
    float s = b0[j];
    for (int i = 0; i < Ko; ++i) s = fmaf(A[j * Ko + i], v[i], s);
    out[j] = s;
}

// ---------------- fp32 tiled GEMM: C = A @ W^T (+bias, relu / split store) ---
// A: [M,K] row-major, W: [N,K] row-major. 128x128 tile, BK=16, 8x8 microtile.
// mode: 0 = bias, 1 = bias+relu, 2 = bias + split store (cols<512 -> first half,
//       cols>=512 -> offset mtot*512)
__global__ __launch_bounds__(256) void gemm_kernel(
    const float* __restrict__ A, const float* __restrict__ W,
    const float* __restrict__ bias, float* __restrict__ C,
    int M, int N, int K, int mode, int mtot)
{
    const int bn = blockIdx.x;
    const int bm = blockIdx.y;
    const int tid = threadIdx.x;
    const int tx = tid & 15, ty = tid >> 4;

    __shared__ float As[16 * 132];
    __shared__ float Bs[16 * 132];

    float acc[8][8];
    #pragma unroll
    for (int i = 0; i < 8; ++i)
        #pragma unroll
        for (int j = 0; j < 8; ++j) acc[i][j] = 0.f;

    const int lrow = tid >> 2;          // 0..63
    const int lk   = (tid & 3) << 2;    // 0,4,8,12
    const int arow0 = bm * 128 + lrow;
    const int arow1 = arow0 + 64;
    const int brow0 = bn * 128 + lrow;
    const int brow1 = brow0 + 64;
    const float* Ap0 = A + (size_t)arow0 * K + lk;
    const float* Ap1 = A + (size_t)arow1 * K + lk;
    const float* Wp0 = W + (size_t)brow0 * K + lk;
    const float* Wp1 = W + (size_t)brow1 * K + lk;
    const bool aval0 = arow0 < M, aval1 = arow1 < M;
    const float4 z4 = make_float4(0.f, 0.f, 0.f, 0.f);

    for (int k0 = 0; k0 < K; k0 += 16) {
        float4 a0 = aval0 ? *(const float4*)(Ap0 + k0) : z4;
        float4 a1 = aval1 ? *(const float4*)(Ap1 + k0) : z4;
        float4 b0 = *(const float4*)(Wp0 + k0);
        float4 b1 = *(const float4*)(Wp1 + k0);
        __syncthreads();
        As[(lk + 0) * 132 + lrow] = a0.x;
        As[(lk + 1) * 132 + lrow] = a0.y;
        As[(lk + 2) * 132 + lrow] = a0.z;
        As[(lk + 3) * 132 + lrow] = a0.w;
        As[(lk + 0) * 132 + lrow + 64] = a1.x;
        As[(lk + 1) * 132 + lrow + 64] = a1.y;
        As[(lk + 2) * 132 + lrow + 64] = a1.z;
        As[(lk + 3) * 132 + lrow + 64] = a1.w;
        Bs[(lk + 0) * 132 + lrow] = b0.x;
        Bs[(lk + 1) * 132 + lrow] = b0.y;
        Bs[(lk + 2) * 132 + lrow] = b0.z;
        Bs[(lk + 3) * 132 + lrow] = b0.w;
        Bs[(lk + 0) * 132 + lrow + 64] = b1.x;
        Bs[(lk + 1) * 132 + lrow + 64] = b1.y;
        Bs[(lk + 2) * 132 + lrow + 64] = b1.z;
        Bs[(lk + 3) * 132 + lrow + 64] = b1.w;
        __syncthreads();

        #pragma unroll
        for (int k = 0; k < 16; ++k) {
            float av[8], bv[8];
            *(float4*)&av[0] = *(const float4*)&As[k * 132 + ty * 8];
            *(float4*)&av[4] = *(const float4*)&As[k * 132 + ty * 8 + 4];
            *(float4*)&bv[0] = *(const float4*)&Bs[k * 132 + tx * 8];
            *(float4*)&bv[4] = *(const float4*)&Bs[k * 132 + tx * 8 + 4];
            #pragma unroll
            for (int i = 0; i < 8; ++i)
                #pragma unroll
                for (int j = 0; j < 8; ++j)
                    acc[i][j] = fmaf(av[i], bv[j], acc[i][j]);
        }
    }

    const int rbase = bm * 128 + ty * 8;
    const int cbase = bn * 128 + tx * 8;
    float bb[8];
    *(float4*)&bb[0] = *(const float4*)&bias[cbase];
    *(float4*)&bb[4] = *(const float4*)&bias[cbase + 4];

    #pragma unroll
    for (int i = 0; i < 8; ++i) {
        int r = rbase + i;
        if (r >= M) continue;
        float v[8];
        #pragma unroll
        for (int j = 0; j < 8; ++j) {
            float u = acc[i][j] + bb[j];
            v[j] = (mode == 1) ? fmaxf(u, 0.f) : u;
        }
        float* dst;
        if (mode == 2) {
            if (cbase < 512) dst = C + (size_t)r * 512 + cbase;
            else             dst = C + (size_t)mtot * 512 + (size_t)r * 512 + (cbase - 512);
        } else {
            dst = C + (size_t)r * N + cbase;
        }
        *(float4*)dst       = *(float4*)&v[0];
        *(float4*)(dst + 4) = *(float4*)&v[4];
    }
}

// ---------------- launch ------------------------------------------------------
extern "C" void kernel_launch(void* const* d_in, const int* in_sizes, int n_in,
                              void* d_out, int out_size, void* d_ws, size_t ws_size,
                              hipStream_t stream)
{
    const float* x     = (const float*)d_in[0];
    const float* aff   = (const float*)d_in[1];
    const float* table = (const float*)d_in[2];
    const float* Wa    = (const float*)d_in[3];
    const float* ba    = (const float*)d_in[4];
    // d_in[5..8] = Wq,bq,Wk,bk — unused (softmax over a single key == 1)
    const float* Wv    = (const float*)d_in[9];
    const float* bv    = (const float*)d_in[10];
    const float* Wo    = (const float*)d_in[11];
    const float* bo    = (const float*)d_in[12];
    const float* W1    = (const float*)d_in[13];
    const float* b1    = (const float*)d_in[14];
    const float* W2    = (const float*)d_in[15];
    const float* b2    = (const float*)d_in[16];
    const float* W3    = (const float*)d_in[17];
    const float* b3    = (const float*)d_in[18];
    const int npts = in_sizes[0] / 3;

    float* ws   = (float*)d_ws;
    float* Wvo  = ws;                       // 128*128
    float* bvo  = ws + 16384;               // 128
    float* W1c  = ws + 16512;               // 256*128
    float* b1c  = ws + 49280;               // 256
    float* comb = ws + 49536;               // npts*128 (region sized npts*256, reused by h2)
    float* h2   = comb;                     // npts*256 (comb is dead by then)
    float* h1   = ws + 49536 + (size_t)npts * 256;  // npts*256

    // fold v/attn linear chain into W1:  h1 = relu(comb @ (W1·Wo·Wv)^T + (W1·(Wo·bv+bo)+b1))
    small_mm<<<64, 256, 0, stream>>>(Wo, Wv, Wvo, 128, 128, 128);
    small_mv<<<1, 256, 0, stream>>>(Wo, bv, bo, bvo, 128, 128);
    small_mm<<<128, 256, 0, stream>>>(W1, Wvo, W1c, 256, 128, 128);
    small_mv<<<1, 256, 0, stream>>>(W1, bvo, b1, b1c, 256, 128);

    grid_encode_kernel<<<(npts * 16 + 255) / 256, 256, 0, stream>>>(
        x, aff, table, Wa, ba, comb, npts);

    const int mb = (npts + 127) / 128;
    // h1 = relu(comb @ W1c^T + b1c)
    gemm_kernel<<<dim3(2, mb), 256, 0, stream>>>(comb, W1c, b1c, h1, npts, 256, 128, 1, npts);
    // h2 = relu(h1 @ W2^T + b2)
    gemm_kernel<<<dim3(2, mb), 256, 0, stream>>>(h1, W2, b2, h2, npts, 256, 256, 1, npts);
    // out = h2 @ W3^T + b3, split-stored as (out[:, :512], out[:, 512:])
    gemm_kernel<<<dim3(8, mb), 256, 0, stream>>>(h2, W3, b3, (float*)d_out, npts, 1024, 256, 2, npts);
}